// Round 3
// baseline (725.338 us; speedup 1.0000x reference)
//
#include <hip/hip_runtime.h>

typedef float f32x4 __attribute__((ext_vector_type(4)));
typedef short short8 __attribute__((ext_vector_type(8)));

#define T_LEN 2048
#define HD 256
#define SD 64
#define DIN 768
#define DOUT 768
#define NCHUNK 32
#define CLEN 64

__device__ __forceinline__ unsigned short f2bf(float f) {
    unsigned int u = __float_as_uint(f);
    unsigned int r = u + 0x7FFFu + ((u >> 16) & 1u);
    return (unsigned short)(r >> 16);
}
__device__ __forceinline__ float bf2f(unsigned short h) {
    return __uint_as_float(((unsigned int)h) << 16);
}
// swizzled element index for row-major bf16 LDS tile (stride elems), XOR on 8-elem groups
__device__ __forceinline__ int swz(int row, int col, int stride) {
    return row * stride + (col ^ ((row & 7) << 3));
}

// ---------------- conversions ----------------
__global__ __launch_bounds__(256) void cvt_x_k(const float* __restrict__ s,
                                               unsigned short* __restrict__ d, int n4) {
    int i = blockIdx.x * 256 + threadIdx.x;
    if (i >= n4) return;
    float4 v = reinterpret_cast<const float4*>(s)[i];
    ushort4 o;
    o.x = f2bf(v.x); o.y = f2bf(v.y); o.z = f2bf(v.z); o.w = f2bf(v.w);
    reinterpret_cast<ushort4*>(d)[i] = o;
}

__global__ __launch_bounds__(256) void cvt_w_k(const float* __restrict__ s0, const float* __restrict__ s1,
                                               const float* __restrict__ s2, const float* __restrict__ s3,
                                               const float* __restrict__ s4, const float* __restrict__ s5,
                                               unsigned short* __restrict__ d) {
    int i = blockIdx.x * 256 + threadIdx.x;
    if (i >= 1048576) return;
    float v;
    if (i < 196608)      v = s0[i];
    else if (i < 262144) v = s1[i - 196608];
    else if (i < 524288) v = s2[i - 262144];
    else if (i < 786432) v = s3[i - 524288];
    else if (i < 851968) v = s4[i - 786432];
    else                 v = s5[i - 851968];
    d[i] = f2bf(v);
}

// ---------------- A^64 via bf16-split MFMA (6 squarings) ----------------
__global__ __launch_bounds__(256) void matpow_k(const float* __restrict__ A, float* __restrict__ Apow) {
    __shared__ unsigned short Mh[4096], Ml[4096], MhT[4096], MlT[4096];
    const int l = blockIdx.x, tid = threadIdx.x;
    const int w = tid >> 6, ln = tid & 63, ll = ln & 15, lh = ln >> 4;
    const float* src = A + l * 4096;
    for (int i = tid; i < 4096; i += 256) {
        float v = src[i];
        unsigned short hi = f2bf(v);
        unsigned short lo = f2bf(v - bf2f(hi));
        int r = i >> 6, c = i & 63;
        Mh[swz(r, c, 64)] = hi;  Ml[swz(r, c, 64)] = lo;
        MhT[swz(c, r, 64)] = hi; MlT[swz(c, r, 64)] = lo;
    }
    __syncthreads();
    for (int it = 0; it < 6; it++) {
        f32x4 acc[4] = {};
#pragma unroll
        for (int ks = 0; ks < 2; ks++) {
            int ar = w * 16 + ll, c0 = ks * 32 + lh * 8;
            short8 ah = *reinterpret_cast<const short8*>(&Mh[swz(ar, c0, 64)]);
            short8 al = *reinterpret_cast<const short8*>(&Ml[swz(ar, c0, 64)]);
#pragma unroll
            for (int nf = 0; nf < 4; nf++) {
                int br = nf * 16 + ll;
                short8 bh = *reinterpret_cast<const short8*>(&MhT[swz(br, c0, 64)]);
                short8 bl = *reinterpret_cast<const short8*>(&MlT[swz(br, c0, 64)]);
                acc[nf] = __builtin_amdgcn_mfma_f32_16x16x32_bf16(ah, bh, acc[nf], 0, 0, 0);
                acc[nf] = __builtin_amdgcn_mfma_f32_16x16x32_bf16(ah, bl, acc[nf], 0, 0, 0);
                acc[nf] = __builtin_amdgcn_mfma_f32_16x16x32_bf16(al, bh, acc[nf], 0, 0, 0);
            }
        }
        __syncthreads();  // all reads done before in-place overwrite
#pragma unroll
        for (int nf = 0; nf < 4; nf++)
#pragma unroll
            for (int r = 0; r < 4; r++) {
                float v = acc[nf][r];
                int row = w * 16 + lh * 4 + r, col = nf * 16 + ll;
                unsigned short hi = f2bf(v);
                unsigned short lo = f2bf(v - bf2f(hi));
                Mh[swz(row, col, 64)] = hi;  Ml[swz(row, col, 64)] = lo;
                MhT[swz(col, row, 64)] = hi; MlT[swz(col, row, 64)] = lo;
            }
        __syncthreads();
    }
    for (int i = tid; i < 4096; i += 256) {
        int r = i >> 6, c = i & 63;
        Apow[l * 4096 + i] = bf2f(Mh[swz(r, c, 64)]) + bf2f(Ml[swz(r, c, 64)]);
    }
}

// ---------------- fused LN + (gate||ip) GEMM ----------------
// block: 64 rows; waves: 4 x 16 rows. N = 256 gate + 64 ip.
__global__ __launch_bounds__(256) void pre_k(const float* __restrict__ h,
                                             const float* __restrict__ g, const float* __restrict__ be,
                                             const unsigned short* __restrict__ wg,
                                             const unsigned short* __restrict__ wip,
                                             const float* __restrict__ gbias, const float* __restrict__ ipb,
                                             const float* __restrict__ Bv, const float* __restrict__ bA,
                                             unsigned short* __restrict__ xnb, unsigned short* __restrict__ gB,
                                             float* __restrict__ u) {
    __shared__ unsigned short As[64 * 256];
    const int tid = threadIdx.x, w = tid >> 6, ln = tid & 63, ll = ln & 15, lh = ln >> 4;
    const int m0 = blockIdx.x * 64;
    // LN phase: wave w -> local rows w*16..+15
    for (int i = 0; i < 16; i++) {
        int rowl = w * 16 + i;
        int row = m0 + rowl;
        const float4 x = *reinterpret_cast<const float4*>(h + (size_t)row * HD + ln * 4);
        float s = x.x + x.y + x.z + x.w;
        float s2 = x.x * x.x + x.y * x.y + x.z * x.z + x.w * x.w;
#pragma unroll
        for (int m = 1; m < 64; m <<= 1) { s += __shfl_xor(s, m); s2 += __shfl_xor(s2, m); }
        float mean = s * (1.f / 256.f);
        float var = s2 * (1.f / 256.f) - mean * mean;
        float rstd = rsqrtf(var + 1e-5f);
        int c = ln * 4;
        ushort4 o;
        o.x = f2bf((x.x - mean) * rstd * g[c + 0] + be[c + 0]);
        o.y = f2bf((x.y - mean) * rstd * g[c + 1] + be[c + 1]);
        o.z = f2bf((x.z - mean) * rstd * g[c + 2] + be[c + 2]);
        o.w = f2bf((x.w - mean) * rstd * g[c + 3] + be[c + 3]);
        *reinterpret_cast<ushort4*>(&As[swz(rowl, c, 256)]) = o;
        *reinterpret_cast<ushort4*>(xnb + (size_t)row * HD + c) = o;
    }
    __syncthreads();
    // MFMA phase: wave w rows w*16..+15, all 320 cols
    f32x4 acc[20] = {};
    const int arow = w * 16 + ll;
#pragma unroll
    for (int ks = 0; ks < 8; ks++) {
        int c0 = ks * 32 + lh * 8;
        short8 a = *reinterpret_cast<const short8*>(&As[swz(arow, c0, 256)]);
#pragma unroll
        for (int nf = 0; nf < 20; nf++) {
            const unsigned short* Wp = (nf < 16) ? (wg + (size_t)(nf * 16 + ll) * HD + c0)
                                                 : (wip + (size_t)((nf - 16) * 16 + ll) * HD + c0);
            short8 b = *reinterpret_cast<const short8*>(Wp);
            acc[nf] = __builtin_amdgcn_mfma_f32_16x16x32_bf16(a, b, acc[nf], 0, 0, 0);
        }
    }
#pragma unroll
    for (int nf = 0; nf < 16; nf++)
#pragma unroll
        for (int r = 0; r < 4; r++) {
            int m = m0 + w * 16 + lh * 4 + r;
            int n = nf * 16 + ll;
            float v = acc[nf][r] + gbias[n];
            float gg = 1.f / (1.f + __expf(-v));
            gB[(size_t)m * HD + n] = f2bf(gg);
        }
#pragma unroll
    for (int nf = 16; nf < 20; nf++)
#pragma unroll
        for (int r = 0; r < 4; r++) {
            int m = m0 + w * 16 + lh * 4 + r;
            int n = (nf - 16) * 16 + ll;
            float v = acc[nf][r] + ipb[n];
            float uu = Bv[n] * v + bA[n];
            int t = m & 2047, b = m >> 11;
            u[((t << 3) + b) * 64 + n] = uu;
        }
}

// ---------------- fused Cm + proj + gated blend ----------------
// rows in tb-order (m = t*8+b). block: 64 rows, 4 waves x 16 rows.
__global__ __launch_bounds__(256) void post_k(const unsigned short* __restrict__ Hs,
                                              const unsigned short* __restrict__ wc,
                                              const float* __restrict__ bC,
                                              const unsigned short* __restrict__ wp,
                                              const float* __restrict__ pb,
                                              const unsigned short* __restrict__ gB,
                                              const unsigned short* __restrict__ xnb,
                                              float* __restrict__ h, unsigned short* __restrict__ hb) {
    __shared__ unsigned short Ys[64 * 256];
    const int tid = threadIdx.x, w = tid >> 6, ln = tid & 63, ll = ln & 15, lh = ln >> 4;
    const int m0 = blockIdx.x * 64;
    // step 1: y = Hs @ Cm^T + bC  (K=64)
    f32x4 acc[16] = {};
#pragma unroll
    for (int ks = 0; ks < 2; ks++) {
        int c0 = ks * 32 + lh * 8;
        short8 a = *reinterpret_cast<const short8*>(Hs + (size_t)(m0 + w * 16 + ll) * SD + c0);
#pragma unroll
        for (int nf = 0; nf < 16; nf++) {
            short8 b = *reinterpret_cast<const short8*>(wc + (size_t)(nf * 16 + ll) * SD + c0);
            acc[nf] = __builtin_amdgcn_mfma_f32_16x16x32_bf16(a, b, acc[nf], 0, 0, 0);
        }
    }
#pragma unroll
    for (int nf = 0; nf < 16; nf++)
#pragma unroll
        for (int r = 0; r < 4; r++) {
            int rowl = w * 16 + lh * 4 + r;
            int n = nf * 16 + ll;
            Ys[swz(rowl, n, 256)] = f2bf(acc[nf][r] + bC[n]);
        }
    __syncthreads();
    // step 2: y2 = y @ proj^T (K=256) + gated blend epilogue
    f32x4 acc2[16] = {};
    const int arow = w * 16 + ll;
#pragma unroll
    for (int ks = 0; ks < 8; ks++) {
        int c0 = ks * 32 + lh * 8;
        short8 a = *reinterpret_cast<const short8*>(&Ys[swz(arow, c0, 256)]);
#pragma unroll
        for (int nf = 0; nf < 16; nf++) {
            short8 b = *reinterpret_cast<const short8*>(wp + (size_t)(nf * 16 + ll) * HD + c0);
            acc2[nf] = __builtin_amdgcn_mfma_f32_16x16x32_bf16(a, b, acc2[nf], 0, 0, 0);
        }
    }
#pragma unroll
    for (int nf = 0; nf < 16; nf++)
#pragma unroll
        for (int r = 0; r < 4; r++) {
            int m = m0 + w * 16 + lh * 4 + r;  // tb-order
            int n = nf * 16 + ll;
            int t = m >> 3, b = m & 7;
            size_t idx = (size_t)(((b << 11) + t)) * HD + n;
            float v = acc2[nf][r] + pb[n];
            float gg = bf2f(gB[idx]);
            float xv = bf2f(xnb[idx]);
            float hn = h[idx] + gg * v + (1.f - gg) * xv;
            h[idx] = hn;
            hb[idx] = f2bf(hn);
        }
}

// ---------------- plain GEMM (in/out projections): out = A@W^T + bias ----------------
template <int K, int N>
__global__ __launch_bounds__(256) void gemm_k(const unsigned short* __restrict__ A,
                                              const unsigned short* __restrict__ W,
                                              const float* __restrict__ bias,
                                              float* __restrict__ outf) {
    const int l = threadIdx.x & 63, w = threadIdx.x >> 6;
    const int ll = l & 15, lh = l >> 4;
    const int m0 = blockIdx.x * 128 + w * 32;
    const int n0 = blockIdx.y * 64;
    f32x4 acc[2][4] = {};
    const unsigned short* Ap = A + (size_t)(m0 + ll) * K + lh * 8;
    const unsigned short* Wp = W + (size_t)(n0 + ll) * K + lh * 8;
#pragma unroll
    for (int k0 = 0; k0 < K; k0 += 32) {
        short8 a0 = *reinterpret_cast<const short8*>(Ap + k0);
        short8 a1 = *reinterpret_cast<const short8*>(Ap + 16 * K + k0);
        short8 b0 = *reinterpret_cast<const short8*>(Wp + k0);
        short8 b1 = *reinterpret_cast<const short8*>(Wp + 16 * K + k0);
        short8 b2 = *reinterpret_cast<const short8*>(Wp + 32 * K + k0);
        short8 b3 = *reinterpret_cast<const short8*>(Wp + 48 * K + k0);
        acc[0][0] = __builtin_amdgcn_mfma_f32_16x16x32_bf16(a0, b0, acc[0][0], 0, 0, 0);
        acc[0][1] = __builtin_amdgcn_mfma_f32_16x16x32_bf16(a0, b1, acc[0][1], 0, 0, 0);
        acc[0][2] = __builtin_amdgcn_mfma_f32_16x16x32_bf16(a0, b2, acc[0][2], 0, 0, 0);
        acc[0][3] = __builtin_amdgcn_mfma_f32_16x16x32_bf16(a0, b3, acc[0][3], 0, 0, 0);
        acc[1][0] = __builtin_amdgcn_mfma_f32_16x16x32_bf16(a1, b0, acc[1][0], 0, 0, 0);
        acc[1][1] = __builtin_amdgcn_mfma_f32_16x16x32_bf16(a1, b1, acc[1][1], 0, 0, 0);
        acc[1][2] = __builtin_amdgcn_mfma_f32_16x16x32_bf16(a1, b2, acc[1][2], 0, 0, 0);
        acc[1][3] = __builtin_amdgcn_mfma_f32_16x16x32_bf16(a1, b3, acc[1][3], 0, 0, 0);
    }
#pragma unroll
    for (int mf = 0; mf < 2; mf++)
#pragma unroll
        for (int nf = 0; nf < 4; nf++)
#pragma unroll
            for (int r = 0; r < 4; r++) {
                int m = m0 + mf * 16 + lh * 4 + r;
                int n = n0 + nf * 16 + ll;
                outf[(size_t)m * N + n] = acc[mf][nf][r] + bias[n];
            }
}

// ---------------- scan helpers ----------------
__device__ __forceinline__ void loadA64(const float* __restrict__ Af, int s, float* a) {
#pragma unroll
    for (int q = 0; q < 16; q++) {
        float4 v = reinterpret_cast<const float4*>(Af + s * 64)[q];
        a[q * 4 + 0] = v.x; a[q * 4 + 1] = v.y; a[q * 4 + 2] = v.z; a[q * 4 + 3] = v.w;
    }
}

__device__ __forceinline__ float step64(const float* a, float h, float uu) {
    float ac0 = uu, ac1 = 0.f, ac2 = 0.f, ac3 = 0.f;
#pragma unroll
    for (int k = 0; k < 64; k += 4) {
        float b0 = __int_as_float(__builtin_amdgcn_readlane(__float_as_int(h), k + 0));
        float b1 = __int_as_float(__builtin_amdgcn_readlane(__float_as_int(h), k + 1));
        float b2 = __int_as_float(__builtin_amdgcn_readlane(__float_as_int(h), k + 2));
        float b3 = __int_as_float(__builtin_amdgcn_readlane(__float_as_int(h), k + 3));
        ac0 = fmaf(b0, a[k + 0], ac0);
        ac1 = fmaf(b1, a[k + 1], ac1);
        ac2 = fmaf(b2, a[k + 2], ac2);
        ac3 = fmaf(b3, a[k + 3], ac3);
    }
    return (ac0 + ac1) + (ac2 + ac3);
}

__global__ __launch_bounds__(64) void scan_chunk_k(const float* __restrict__ Af,
                                                   const float* __restrict__ u,
                                                   float* __restrict__ Slast) {
    const int c = blockIdx.x >> 3, b = blockIdx.x & 7;
    const int s = threadIdx.x;
    float a[64];
    loadA64(Af, s, a);
    const float* up = u + (c * CLEN) * 512 + b * 64 + s;
    float h = 0.f;
    float un = up[0];
    for (int i = 0; i < CLEN; i++) {
        float uu = un;
        if (i < CLEN - 1) un = up[(i + 1) * 512];
        h = step64(a, h, uu);
    }
    Slast[blockIdx.x * 64 + s] = h;
}

__global__ __launch_bounds__(64) void carry_k(const float* __restrict__ Apow,
                                              const float* __restrict__ Slast,
                                              float* __restrict__ Carry) {
    const int b = blockIdx.x;
    const int s = threadIdx.x;
    float a[64];
    loadA64(Apow, s, a);
    float carry = 0.f;
    float sl = Slast[b * 64 + s];
    for (int c = 0; c < NCHUNK; c++) {
        Carry[(c * 8 + b) * 64 + s] = carry;
        float sl_cur = sl;
        if (c < NCHUNK - 1) sl = Slast[((c + 1) * 8 + b) * 64 + s];
        carry = step64(a, carry, sl_cur);
    }
}

__global__ __launch_bounds__(64) void replay_k(const float* __restrict__ Af,
                                               const float* __restrict__ u,
                                               const float* __restrict__ Carry,
                                               unsigned short* __restrict__ Hs,
                                               int* __restrict__ flag) {
    const int c = blockIdx.x >> 3, b = blockIdx.x & 7;
    const int s = threadIdx.x;
    float a[64];
    loadA64(Af, s, a);
    float h = Carry[blockIdx.x * 64 + s];
    const float* up = u + (c * CLEN) * 512 + b * 64 + s;
    unsigned short* hp = Hs + (c * CLEN) * 512 + b * 64 + s;
    bool bad = false;
    float un = up[0];
    for (int i = 0; i < CLEN; i++) {
        float uu = un;
        if (i < CLEN - 1) un = up[(i + 1) * 512];
        h = step64(a, h, uu);
        bad |= (fabsf(h) > 10.f);
        hp[i * 512] = f2bf(h);
    }
    if (__any(bad ? 1 : 0)) {
        if (s == 0) atomicOr(flag, 1);
    }
}

__global__ __launch_bounds__(64) void scan_seq_k(const float* __restrict__ Af,
                                                 const float* __restrict__ u,
                                                 unsigned short* __restrict__ Hs,
                                                 const int* __restrict__ flag) {
    if (*flag == 0) return;
    const int b = blockIdx.x;
    const int s = threadIdx.x;
    float a[64];
    loadA64(Af, s, a);
    float h = 0.f;
    for (int t = 0; t < T_LEN; t++) {
        float uu = u[((t << 3) + b) * 64 + s];
        float hp = step64(a, h, uu);
        h = fminf(fmaxf(hp, -10.f), 10.f);
        Hs[((t << 3) + b) * 64 + s] = f2bf(h);
    }
}

// ---------------- launch ----------------
extern "C" void kernel_launch(void* const* d_in, const int* in_sizes, int n_in,
                              void* d_out, int out_size, void* d_ws, size_t ws_size,
                              hipStream_t stream) {
    const float* x    = (const float*)d_in[0];
    const float* inw  = (const float*)d_in[1];
    const float* inb  = (const float*)d_in[2];
    const float* lng  = (const float*)d_in[3];
    const float* lnb  = (const float*)d_in[4];
    const float* ipw  = (const float*)d_in[5];
    const float* ipb  = (const float*)d_in[6];
    const float* Amat = (const float*)d_in[7];
    const float* Bv   = (const float*)d_in[8];
    const float* Cm   = (const float*)d_in[9];
    const float* bA   = (const float*)d_in[10];
    const float* bC   = (const float*)d_in[11];
    const float* gw   = (const float*)d_in[12];
    const float* gbia = (const float*)d_in[13];
    const float* pw   = (const float*)d_in[14];
    const float* pb   = (const float*)d_in[15];
    const float* ow   = (const float*)d_in[16];
    const float* ob   = (const float*)d_in[17];

    char* ws = (char*)d_ws;
    unsigned short* xb = (unsigned short*)(ws + 0);          // 25165824 B (reused below)
    float*          u  = (float*)(ws + 0);                   // 4 MB
    unsigned short* Hs = (unsigned short*)(ws + 4194304);    // 2 MB
    unsigned short* hb = (unsigned short*)(ws + 14680064);   // 8 MB
    unsigned short* wb = (unsigned short*)(ws + 25165824);   // 2 MB
    float*          h  = (float*)(ws + 27262976);            // 16 MB
    unsigned short* xnb = (unsigned short*)(ws + 44040192);  // 8 MB
    unsigned short* gB  = (unsigned short*)(ws + 52428800);  // 8 MB

    char* sc = (char*)d_out;   // scratch in d_out; fully overwritten by final GEMM
    float* Apow  = (float*)(sc + 0);
    float* Slast = (float*)(sc + 65536);
    float* Carry = (float*)(sc + 131072);
    int*   flag  = (int*)(sc + 196608);

    const unsigned short* w_in = wb + 0;
    const unsigned short* w_ip = wb + 196608;
    const unsigned short* w_g  = wb + 262144;
    const unsigned short* w_p  = wb + 524288;
    const unsigned short* w_c  = wb + 786432;
    const unsigned short* w_o  = wb + 851968;

    hipMemsetAsync(flag, 0, 16, stream);
    cvt_x_k<<<12288, 256, 0, stream>>>(x, xb, 3145728);
    cvt_w_k<<<4096, 256, 0, stream>>>(inw, ipw, gw, pw, Cm, ow, wb);
    matpow_k<<<4, 256, 0, stream>>>(Amat, Apow);

    gemm_k<DIN, HD><<<dim3(128, 4), 256, 0, stream>>>(xb, w_in, inb, h);
    for (int i = 0; i < 4; i++) {
        pre_k<<<256, 256, 0, stream>>>(h, lng + i * HD, lnb + i * HD,
                                       w_g + i * 65536, w_ip + i * 16384,
                                       gbia + i * HD, ipb + i * SD,
                                       Bv + i * SD, bA + i * SD, xnb, gB, u);
        scan_chunk_k<<<256, 64, 0, stream>>>(Amat + i * 4096, u, Slast);
        carry_k<<<8, 64, 0, stream>>>(Apow + i * 4096, Slast, Carry);
        replay_k<<<256, 64, 0, stream>>>(Amat + i * 4096, u, Carry, Hs, flag + i);
        scan_seq_k<<<8, 64, 0, stream>>>(Amat + i * 4096, u, Hs, flag + i);
        post_k<<<256, 256, 0, stream>>>(Hs, w_c + i * 16384, bC + i * HD,
                                        w_p + i * 65536, pb + i * HD, gB, xnb, h, hb);
    }
    gemm_k<HD, DOUT><<<dim3(128, 12), 256, 0, stream>>>(hb, w_o, ob, (float*)d_out);
}

// Round 4
// 554.652 us; speedup vs baseline: 1.3077x; 1.3077x over previous
//
#include <hip/hip_runtime.h>

typedef float f32x4 __attribute__((ext_vector_type(4)));
typedef short short8 __attribute__((ext_vector_type(8)));

#define T_LEN 2048
#define HD 256
#define SD 64
#define DIN 768
#define DOUT 768
#define NCHUNK 32
#define CLEN 64

__device__ __forceinline__ unsigned short f2bf(float f) {
    unsigned int u = __float_as_uint(f);
    unsigned int r = u + 0x7FFFu + ((u >> 16) & 1u);
    return (unsigned short)(r >> 16);
}
__device__ __forceinline__ float bf2f(unsigned short h) {
    return __uint_as_float(((unsigned int)h) << 16);
}
__device__ __forceinline__ int swz(int row, int col, int stride) {
    return row * stride + (col ^ ((row & 7) << 3));
}

// ---------------- conversions ----------------
__global__ __launch_bounds__(256) void cvt_x_k(const float* __restrict__ s,
                                               unsigned short* __restrict__ d, int n4) {
    int i = blockIdx.x * 256 + threadIdx.x;
    if (i >= n4) return;
    float4 v = reinterpret_cast<const float4*>(s)[i];
    ushort4 o;
    o.x = f2bf(v.x); o.y = f2bf(v.y); o.z = f2bf(v.z); o.w = f2bf(v.w);
    reinterpret_cast<ushort4*>(d)[i] = o;
}

__global__ __launch_bounds__(256) void cvt_w_k(const float* __restrict__ s0, const float* __restrict__ s1,
                                               const float* __restrict__ s2, const float* __restrict__ s3,
                                               const float* __restrict__ s4, const float* __restrict__ s5,
                                               unsigned short* __restrict__ d) {
    int i = blockIdx.x * 256 + threadIdx.x;
    if (i >= 1048576) return;
    float v;
    if (i < 196608)      v = s0[i];
    else if (i < 262144) v = s1[i - 196608];
    else if (i < 524288) v = s2[i - 262144];
    else if (i < 786432) v = s3[i - 524288];
    else if (i < 851968) v = s4[i - 786432];
    else                 v = s5[i - 851968];
    d[i] = f2bf(v);
}

// ---------------- A^64 via bf16-split MFMA (6 squarings), verified round 3 ----------------
__global__ __launch_bounds__(256) void matpow_k(const float* __restrict__ A, float* __restrict__ Apow) {
    __shared__ unsigned short Mh[4096], Ml[4096], MhT[4096], MlT[4096];
    const int l = blockIdx.x, tid = threadIdx.x;
    const int w = tid >> 6, ln = tid & 63, ll = ln & 15, lh = ln >> 4;
    const float* src = A + l * 4096;
    for (int i = tid; i < 4096; i += 256) {
        float v = src[i];
        unsigned short hi = f2bf(v);
        unsigned short lo = f2bf(v - bf2f(hi));
        int r = i >> 6, c = i & 63;
        Mh[swz(r, c, 64)] = hi;  Ml[swz(r, c, 64)] = lo;
        MhT[swz(c, r, 64)] = hi; MlT[swz(c, r, 64)] = lo;
    }
    __syncthreads();
    for (int it = 0; it < 6; it++) {
        f32x4 acc[4] = {};
#pragma unroll
        for (int ks = 0; ks < 2; ks++) {
            int ar = w * 16 + ll, c0 = ks * 32 + lh * 8;
            short8 ah = *reinterpret_cast<const short8*>(&Mh[swz(ar, c0, 64)]);
            short8 al = *reinterpret_cast<const short8*>(&Ml[swz(ar, c0, 64)]);
#pragma unroll
            for (int nf = 0; nf < 4; nf++) {
                int br = nf * 16 + ll;
                short8 bh = *reinterpret_cast<const short8*>(&MhT[swz(br, c0, 64)]);
                short8 bl = *reinterpret_cast<const short8*>(&MlT[swz(br, c0, 64)]);
                acc[nf] = __builtin_amdgcn_mfma_f32_16x16x32_bf16(ah, bh, acc[nf], 0, 0, 0);
                acc[nf] = __builtin_amdgcn_mfma_f32_16x16x32_bf16(ah, bl, acc[nf], 0, 0, 0);
                acc[nf] = __builtin_amdgcn_mfma_f32_16x16x32_bf16(al, bh, acc[nf], 0, 0, 0);
            }
        }
        __syncthreads();
#pragma unroll
        for (int nf = 0; nf < 4; nf++)
#pragma unroll
            for (int r = 0; r < 4; r++) {
                float v = acc[nf][r];
                int row = w * 16 + lh * 4 + r, col = nf * 16 + ll;
                unsigned short hi = f2bf(v);
                unsigned short lo = f2bf(v - bf2f(hi));
                Mh[swz(row, col, 64)] = hi;  Ml[swz(row, col, 64)] = lo;
                MhT[swz(col, row, 64)] = hi; MlT[swz(col, row, 64)] = lo;
            }
        __syncthreads();
    }
    for (int i = tid; i < 4096; i += 256) {
        int r = i >> 6, c = i & 63;
        Apow[l * 4096 + i] = bf2f(Mh[swz(r, c, 64)]) + bf2f(Ml[swz(r, c, 64)]);
    }
}

// ---------------- LayerNorm: h fp32 -> xn bf16 ----------------
__global__ __launch_bounds__(256) void ln_k(const float* __restrict__ h, const float* __restrict__ g,
                                            const float* __restrict__ be, unsigned short* __restrict__ xnb) {
    int row = blockIdx.x * 4 + (threadIdx.x >> 6);
    int l = threadIdx.x & 63;
    const float4 x = *reinterpret_cast<const float4*>(h + row * HD + l * 4);
    float s = x.x + x.y + x.z + x.w;
    float s2 = x.x * x.x + x.y * x.y + x.z * x.z + x.w * x.w;
#pragma unroll
    for (int m = 1; m < 64; m <<= 1) { s += __shfl_xor(s, m); s2 += __shfl_xor(s2, m); }
    float mean = s * (1.f / 256.f);
    float var = s2 * (1.f / 256.f) - mean * mean;
    float rstd = rsqrtf(var + 1e-5f);
    int c = l * 4;
    ushort4 o;
    o.x = f2bf((x.x - mean) * rstd * g[c + 0] + be[c + 0]);
    o.y = f2bf((x.y - mean) * rstd * g[c + 1] + be[c + 1]);
    o.z = f2bf((x.z - mean) * rstd * g[c + 2] + be[c + 2]);
    o.w = f2bf((x.w - mean) * rstd * g[c + 3] + be[c + 3]);
    *reinterpret_cast<ushort4*>(xnb + row * HD + l * 4) = o;
}

// ---------------- GEMM: out = A[M,K](bf16) @ W[N,K]^T + bias, epilogue by MODE ----------------
// MODE 0: outf[m*N+n] = v
// MODE 1: u = aux0[n]*v + aux1[n] -> outf[((t*8)+b)*64+n], m = b*2048+t
// MODE 2: outb = bf16(sigmoid(v))
// MODE 3: outb = bf16(v)
// MODE 4: m in tb-order; hn = h + g*v + (1-g)*xn; outf=h upd, outb=bf16(hn)
template <int K, int N, int MODE, int BM>
__global__ __launch_bounds__(256) void gemm_k(const unsigned short* __restrict__ A,
                                              const unsigned short* __restrict__ W,
                                              const float* __restrict__ bias,
                                              float* __restrict__ outf, unsigned short* __restrict__ outb,
                                              const float* __restrict__ aux0, const float* __restrict__ aux1,
                                              const unsigned short* __restrict__ gb,
                                              const unsigned short* __restrict__ xnb) {
    const int l = threadIdx.x & 63, w = threadIdx.x >> 6;
    const int ll = l & 15, lh = l >> 4;
    constexpr int MF = BM / 64;  // 16-row fragments per wave
    const int m0 = blockIdx.x * BM + w * (16 * MF);
    const int n0 = blockIdx.y * 64;
    f32x4 acc[MF][4] = {};
    const unsigned short* Ap = A + (size_t)(m0 + ll) * K + lh * 8;
    const unsigned short* Wp = W + (size_t)(n0 + ll) * K + lh * 8;
#pragma unroll
    for (int k0 = 0; k0 < K; k0 += 32) {
        short8 a[MF], b[4];
#pragma unroll
        for (int mf = 0; mf < MF; mf++)
            a[mf] = *reinterpret_cast<const short8*>(Ap + (size_t)mf * 16 * K + k0);
#pragma unroll
        for (int nf = 0; nf < 4; nf++)
            b[nf] = *reinterpret_cast<const short8*>(Wp + (size_t)nf * 16 * K + k0);
#pragma unroll
        for (int mf = 0; mf < MF; mf++)
#pragma unroll
            for (int nf = 0; nf < 4; nf++)
                acc[mf][nf] = __builtin_amdgcn_mfma_f32_16x16x32_bf16(a[mf], b[nf], acc[mf][nf], 0, 0, 0);
    }
#pragma unroll
    for (int mf = 0; mf < MF; mf++)
#pragma unroll
        for (int nf = 0; nf < 4; nf++)
#pragma unroll
            for (int r = 0; r < 4; r++) {
                int m = m0 + mf * 16 + lh * 4 + r;
                int n = n0 + nf * 16 + ll;
                float v = acc[mf][nf][r] + bias[n];
                if constexpr (MODE == 0) {
                    outf[(size_t)m * N + n] = v;
                } else if constexpr (MODE == 1) {
                    float uu = aux0[n] * v + aux1[n];
                    int t = m & 2047, b2 = m >> 11;
                    outf[((t << 3) + b2) * 64 + n] = uu;
                } else if constexpr (MODE == 2) {
                    float gg = 1.f / (1.f + __expf(-v));
                    outb[(size_t)m * N + n] = f2bf(gg);
                } else if constexpr (MODE == 3) {
                    outb[(size_t)m * N + n] = f2bf(v);
                } else if constexpr (MODE == 4) {
                    int t = m >> 3, b2 = m & 7;
                    size_t idx = (size_t)(((b2 << 11) + t)) * HD + n;
                    float g = bf2f(gb[idx]);
                    float xv = bf2f(xnb[idx]);
                    float hn = outf[idx] + g * v + (1.f - g) * xv;
                    outf[idx] = hn;
                    outb[idx] = f2bf(hn);
                }
            }
}

// ---------------- scan helpers ----------------
__device__ __forceinline__ void loadA64(const float* __restrict__ Af, int s, float* a) {
#pragma unroll
    for (int q = 0; q < 16; q++) {
        float4 v = reinterpret_cast<const float4*>(Af + s * 64)[q];
        a[q * 4 + 0] = v.x; a[q * 4 + 1] = v.y; a[q * 4 + 2] = v.z; a[q * 4 + 3] = v.w;
    }
}

__device__ __forceinline__ float step64(const float* a, float h, float uu) {
    float ac0 = uu, ac1 = 0.f, ac2 = 0.f, ac3 = 0.f;
#pragma unroll
    for (int k = 0; k < 64; k += 4) {
        float b0 = __int_as_float(__builtin_amdgcn_readlane(__float_as_int(h), k + 0));
        float b1 = __int_as_float(__builtin_amdgcn_readlane(__float_as_int(h), k + 1));
        float b2 = __int_as_float(__builtin_amdgcn_readlane(__float_as_int(h), k + 2));
        float b3 = __int_as_float(__builtin_amdgcn_readlane(__float_as_int(h), k + 3));
        ac0 = fmaf(b0, a[k + 0], ac0);
        ac1 = fmaf(b1, a[k + 1], ac1);
        ac2 = fmaf(b2, a[k + 2], ac2);
        ac3 = fmaf(b3, a[k + 3], ac3);
    }
    return (ac0 + ac1) + (ac2 + ac3);
}

__global__ __launch_bounds__(64) void scan_chunk_k(const float* __restrict__ Af,
                                                   const float* __restrict__ u,
                                                   float* __restrict__ Slast) {
    const int c = blockIdx.x >> 3, b = blockIdx.x & 7;
    const int s = threadIdx.x;
    float a[64];
    loadA64(Af, s, a);
    const float* up = u + (c * CLEN) * 512 + b * 64 + s;
    float h = 0.f;
    float un = up[0];
    for (int i = 0; i < CLEN; i++) {
        float uu = un;
        if (i < CLEN - 1) un = up[(i + 1) * 512];
        h = step64(a, h, uu);
    }
    Slast[blockIdx.x * 64 + s] = h;
}

__global__ __launch_bounds__(64) void carry_k(const float* __restrict__ Apow,
                                              const float* __restrict__ Slast,
                                              float* __restrict__ Carry) {
    const int b = blockIdx.x;
    const int s = threadIdx.x;
    float a[64];
    loadA64(Apow, s, a);
    float carry = 0.f;
    float sl = Slast[b * 64 + s];
    for (int c = 0; c < NCHUNK; c++) {
        Carry[(c * 8 + b) * 64 + s] = carry;
        float sl_cur = sl;
        if (c < NCHUNK - 1) sl = Slast[((c + 1) * 8 + b) * 64 + s];
        carry = step64(a, carry, sl_cur);
    }
}

__global__ __launch_bounds__(64) void replay_k(const float* __restrict__ Af,
                                               const float* __restrict__ u,
                                               const float* __restrict__ Carry,
                                               unsigned short* __restrict__ Hs,
                                               int* __restrict__ flag) {
    const int c = blockIdx.x >> 3, b = blockIdx.x & 7;
    const int s = threadIdx.x;
    float a[64];
    loadA64(Af, s, a);
    float h = Carry[blockIdx.x * 64 + s];
    const float* up = u + (c * CLEN) * 512 + b * 64 + s;
    unsigned short* hp = Hs + (c * CLEN) * 512 + b * 64 + s;
    bool bad = false;
    float un = up[0];
    for (int i = 0; i < CLEN; i++) {
        float uu = un;
        if (i < CLEN - 1) un = up[(i + 1) * 512];
        h = step64(a, h, uu);
        bad |= (fabsf(h) > 10.f);
        hp[i * 512] = f2bf(h);
    }
    if (__any(bad ? 1 : 0)) {
        if (s == 0) atomicOr(flag, 1);
    }
}

__global__ __launch_bounds__(64) void scan_seq_k(const float* __restrict__ Af,
                                                 const float* __restrict__ u,
                                                 unsigned short* __restrict__ Hs,
                                                 const int* __restrict__ flag) {
    if (*flag == 0) return;
    const int b = blockIdx.x;
    const int s = threadIdx.x;
    float a[64];
    loadA64(Af, s, a);
    float h = 0.f;
    for (int t = 0; t < T_LEN; t++) {
        float uu = u[((t << 3) + b) * 64 + s];
        float hp = step64(a, h, uu);
        h = fminf(fmaxf(hp, -10.f), 10.f);
        Hs[((t << 3) + b) * 64 + s] = f2bf(h);
    }
}

// ---------------- launch ----------------
extern "C" void kernel_launch(void* const* d_in, const int* in_sizes, int n_in,
                              void* d_out, int out_size, void* d_ws, size_t ws_size,
                              hipStream_t stream) {
    const float* x    = (const float*)d_in[0];
    const float* inw  = (const float*)d_in[1];
    const float* inb  = (const float*)d_in[2];
    const float* lng  = (const float*)d_in[3];
    const float* lnb  = (const float*)d_in[4];
    const float* ipw  = (const float*)d_in[5];
    const float* ipb  = (const float*)d_in[6];
    const float* Amat = (const float*)d_in[7];
    const float* Bv   = (const float*)d_in[8];
    const float* Cm   = (const float*)d_in[9];
    const float* bA   = (const float*)d_in[10];
    const float* bC   = (const float*)d_in[11];
    const float* gw   = (const float*)d_in[12];
    const float* gbia = (const float*)d_in[13];
    const float* pw   = (const float*)d_in[14];
    const float* pb   = (const float*)d_in[15];
    const float* ow   = (const float*)d_in[16];
    const float* ob   = (const float*)d_in[17];

    char* ws = (char*)d_ws;
    unsigned short* xb = (unsigned short*)(ws + 0);          // 24 MB (reused below)
    float*          u  = (float*)(ws + 0);                   // 4 MB
    unsigned short* Hs = (unsigned short*)(ws + 4194304);    // 2 MB
    unsigned short* yb = (unsigned short*)(ws + 6291456);    // 8 MB
    unsigned short* hb = (unsigned short*)(ws + 14680064);   // 8 MB
    unsigned short* wb = (unsigned short*)(ws + 25165824);   // 2 MB
    float*          h  = (float*)(ws + 27262976);            // 16 MB
    unsigned short* xnb = (unsigned short*)(ws + 44040192);  // 8 MB
    unsigned short* gB  = (unsigned short*)(ws + 52428800);  // 8 MB

    char* sc = (char*)d_out;   // small scratch; fully overwritten by final GEMM
    float* Apow  = (float*)(sc + 0);
    float* Slast = (float*)(sc + 65536);
    float* Carry = (float*)(sc + 131072);
    int*   flag  = (int*)(sc + 196608);

    const unsigned short* w_in = wb + 0;
    const unsigned short* w_ip = wb + 196608;
    const unsigned short* w_g  = wb + 262144;
    const unsigned short* w_p  = wb + 524288;
    const unsigned short* w_c  = wb + 786432;
    const unsigned short* w_o  = wb + 851968;

    hipMemsetAsync(flag, 0, 16, stream);
    cvt_x_k<<<12288, 256, 0, stream>>>(x, xb, 3145728);
    cvt_w_k<<<4096, 256, 0, stream>>>(inw, ipw, gw, pw, Cm, ow, wb);
    matpow_k<<<4, 256, 0, stream>>>(Amat, Apow);

    gemm_k<DIN, HD, 0, 128><<<dim3(128, 4), 256, 0, stream>>>(xb, w_in, inb, h, nullptr,
                                                              nullptr, nullptr, nullptr, nullptr);
    for (int i = 0; i < 4; i++) {
        ln_k<<<4096, 256, 0, stream>>>(h, lng + i * HD, lnb + i * HD, xnb);
        gemm_k<HD, SD, 1, 64><<<dim3(256, 1), 256, 0, stream>>>(xnb, w_ip + i * 16384, ipb + i * SD,
                                                                u, nullptr, Bv + i * SD, bA + i * SD,
                                                                nullptr, nullptr);
        gemm_k<HD, HD, 2, 128><<<dim3(128, 4), 256, 0, stream>>>(xnb, w_g + i * 65536, gbia + i * HD,
                                                                 nullptr, gB, nullptr, nullptr,
                                                                 nullptr, nullptr);
        scan_chunk_k<<<256, 64, 0, stream>>>(Amat + i * 4096, u, Slast);
        carry_k<<<8, 64, 0, stream>>>(Apow + i * 4096, Slast, Carry);
        replay_k<<<256, 64, 0, stream>>>(Amat + i * 4096, u, Carry, Hs, flag + i);
        scan_seq_k<<<8, 64, 0, stream>>>(Amat + i * 4096, u, Hs, flag + i);
        gemm_k<SD, HD, 3, 128><<<dim3(128, 4), 256, 0, stream>>>(Hs, w_c + i * 16384, bC + i * HD,
                                                                 nullptr, yb, nullptr, nullptr,
                                                                 nullptr, nullptr);
        gemm_k<HD, HD, 4, 128><<<dim3(128, 4), 256, 0, stream>>>(yb, w_p + i * 65536, pb + i * HD,
                                                                 h, hb, nullptr, nullptr, gB, xnb);
    }
    gemm_k<HD, DOUT, 0, 128><<<dim3(128, 12), 256, 0, stream>>>(hb, w_o, ob, (float*)d_out, nullptr,
                                                                nullptr, nullptr, nullptr, nullptr);
}

// Round 5
// 529.750 us; speedup vs baseline: 1.3692x; 1.0470x over previous
//
#include <hip/hip_runtime.h>

typedef float f32x4 __attribute__((ext_vector_type(4)));
typedef short short8 __attribute__((ext_vector_type(8)));

#define T_LEN 2048
#define HD 256
#define SD 64
#define DIN 768
#define DOUT 768
#define NCHUNK 32
#define CLEN 64

__device__ __forceinline__ unsigned short f2bf(float f) {
    unsigned int u = __float_as_uint(f);
    unsigned int r = u + 0x7FFFu + ((u >> 16) & 1u);
    return (unsigned short)(r >> 16);
}
__device__ __forceinline__ float bf2f(unsigned short h) {
    return __uint_as_float(((unsigned int)h) << 16);
}
__device__ __forceinline__ int swz(int row, int col, int stride) {
    return row * stride + (col ^ ((row & 7) << 3));
}

// ---------------- conversions ----------------
__global__ __launch_bounds__(256) void cvt_x_k(const float* __restrict__ s,
                                               unsigned short* __restrict__ d, int n4) {
    int i = blockIdx.x * 256 + threadIdx.x;
    if (i >= n4) return;
    float4 v = reinterpret_cast<const float4*>(s)[i];
    ushort4 o;
    o.x = f2bf(v.x); o.y = f2bf(v.y); o.z = f2bf(v.z); o.w = f2bf(v.w);
    reinterpret_cast<ushort4*>(d)[i] = o;
}

__global__ __launch_bounds__(256) void cvt_w_k(const float* __restrict__ s0, const float* __restrict__ s1,
                                               const float* __restrict__ s2, const float* __restrict__ s3,
                                               const float* __restrict__ s4, const float* __restrict__ s5,
                                               unsigned short* __restrict__ d) {
    int i = blockIdx.x * 256 + threadIdx.x;
    if (i >= 1048576) return;
    float v;
    if (i < 196608)      v = s0[i];
    else if (i < 262144) v = s1[i - 196608];
    else if (i < 524288) v = s2[i - 262144];
    else if (i < 786432) v = s3[i - 524288];
    else if (i < 851968) v = s4[i - 786432];
    else                 v = s5[i - 851968];
    d[i] = f2bf(v);
}

// ---------------- A^64 via bf16-split MFMA (verified) ----------------
__global__ __launch_bounds__(256) void matpow_k(const float* __restrict__ A, float* __restrict__ Apow) {
    __shared__ unsigned short Mh[4096], Ml[4096], MhT[4096], MlT[4096];
    const int l = blockIdx.x, tid = threadIdx.x;
    const int w = tid >> 6, ln = tid & 63, ll = ln & 15, lh = ln >> 4;
    const float* src = A + l * 4096;
    for (int i = tid; i < 4096; i += 256) {
        float v = src[i];
        unsigned short hi = f2bf(v);
        unsigned short lo = f2bf(v - bf2f(hi));
        int r = i >> 6, c = i & 63;
        Mh[swz(r, c, 64)] = hi;  Ml[swz(r, c, 64)] = lo;
        MhT[swz(c, r, 64)] = hi; MlT[swz(c, r, 64)] = lo;
    }
    __syncthreads();
    for (int it = 0; it < 6; it++) {
        f32x4 acc[4] = {};
#pragma unroll
        for (int ks = 0; ks < 2; ks++) {
            int ar = w * 16 + ll, c0 = ks * 32 + lh * 8;
            short8 ah = *reinterpret_cast<const short8*>(&Mh[swz(ar, c0, 64)]);
            short8 al = *reinterpret_cast<const short8*>(&Ml[swz(ar, c0, 64)]);
#pragma unroll
            for (int nf = 0; nf < 4; nf++) {
                int br = nf * 16 + ll;
                short8 bh = *reinterpret_cast<const short8*>(&MhT[swz(br, c0, 64)]);
                short8 bl = *reinterpret_cast<const short8*>(&MlT[swz(br, c0, 64)]);
                acc[nf] = __builtin_amdgcn_mfma_f32_16x16x32_bf16(ah, bh, acc[nf], 0, 0, 0);
                acc[nf] = __builtin_amdgcn_mfma_f32_16x16x32_bf16(ah, bl, acc[nf], 0, 0, 0);
                acc[nf] = __builtin_amdgcn_mfma_f32_16x16x32_bf16(al, bh, acc[nf], 0, 0, 0);
            }
        }
        __syncthreads();
#pragma unroll
        for (int nf = 0; nf < 4; nf++)
#pragma unroll
            for (int r = 0; r < 4; r++) {
                float v = acc[nf][r];
                int row = w * 16 + lh * 4 + r, col = nf * 16 + ll;
                unsigned short hi = f2bf(v);
                unsigned short lo = f2bf(v - bf2f(hi));
                Mh[swz(row, col, 64)] = hi;  Ml[swz(row, col, 64)] = lo;
                MhT[swz(col, row, 64)] = hi; MlT[swz(col, row, 64)] = lo;
            }
        __syncthreads();
    }
    for (int i = tid; i < 4096; i += 256) {
        int r = i >> 6, c = i & 63;
        Apow[l * 4096 + i] = bf2f(Mh[swz(r, c, 64)]) + bf2f(Ml[swz(r, c, 64)]);
    }
}

// ---------------- LayerNorm ----------------
__global__ __launch_bounds__(256) void ln_k(const float* __restrict__ h, const float* __restrict__ g,
                                            const float* __restrict__ be, unsigned short* __restrict__ xnb) {
    int row = blockIdx.x * 4 + (threadIdx.x >> 6);
    int l = threadIdx.x & 63;
    const float4 x = *reinterpret_cast<const float4*>(h + row * HD + l * 4);
    float s = x.x + x.y + x.z + x.w;
    float s2 = x.x * x.x + x.y * x.y + x.z * x.z + x.w * x.w;
#pragma unroll
    for (int m = 1; m < 64; m <<= 1) { s += __shfl_xor(s, m); s2 += __shfl_xor(s2, m); }
    float mean = s * (1.f / 256.f);
    float var = s2 * (1.f / 256.f) - mean * mean;
    float rstd = rsqrtf(var + 1e-5f);
    int c = l * 4;
    ushort4 o;
    o.x = f2bf((x.x - mean) * rstd * g[c + 0] + be[c + 0]);
    o.y = f2bf((x.y - mean) * rstd * g[c + 1] + be[c + 1]);
    o.z = f2bf((x.z - mean) * rstd * g[c + 2] + be[c + 2]);
    o.w = f2bf((x.w - mean) * rstd * g[c + 3] + be[c + 3]);
    *reinterpret_cast<ushort4*>(xnb + row * HD + l * 4) = o;
}

// ---------------- MFMA core: 128-row tile (4 waves x 32 rows), 64-col tile ----------------
template <int K>
__device__ __forceinline__ void mfma_core(const unsigned short* __restrict__ A,
                                          const unsigned short* __restrict__ W,
                                          int m0, int n0, int ll, int lh, f32x4 (*acc)[4]) {
    const unsigned short* Ap = A + (size_t)(m0 + ll) * K + lh * 8;
    const unsigned short* Wp = W + (size_t)(n0 + ll) * K + lh * 8;
#pragma unroll
    for (int k0 = 0; k0 < K; k0 += 32) {
        short8 a[2], b[4];
#pragma unroll
        for (int mf = 0; mf < 2; mf++)
            a[mf] = *reinterpret_cast<const short8*>(Ap + (size_t)mf * 16 * K + k0);
#pragma unroll
        for (int nf = 0; nf < 4; nf++)
            b[nf] = *reinterpret_cast<const short8*>(Wp + (size_t)nf * 16 * K + k0);
#pragma unroll
        for (int mf = 0; mf < 2; mf++)
#pragma unroll
            for (int nf = 0; nf < 4; nf++)
                acc[mf][nf] = __builtin_amdgcn_mfma_f32_16x16x32_bf16(a[mf], b[nf], acc[mf][nf], 0, 0, 0);
    }
}

// ---------------- plain GEMM, fp32 out, LDS-staged coalesced stores ----------------
template <int K, int N>
__global__ __launch_bounds__(256) void gemm_k(const unsigned short* __restrict__ A,
                                              const unsigned short* __restrict__ W,
                                              const float* __restrict__ bias,
                                              float* __restrict__ outf) {
    __shared__ float sf[128 * 68];
    const int tid = threadIdx.x, l = tid & 63, w = tid >> 6;
    const int ll = l & 15, lh = l >> 4;
    const int m0b = blockIdx.x * 128;
    const int m0 = m0b + w * 32;
    const int n0 = blockIdx.y * 64;
    f32x4 acc[2][4] = {};
    mfma_core<K>(A, W, m0, n0, ll, lh, acc);
#pragma unroll
    for (int mf = 0; mf < 2; mf++)
#pragma unroll
        for (int nf = 0; nf < 4; nf++)
#pragma unroll
            for (int r = 0; r < 4; r++) {
                int rowl = w * 32 + mf * 16 + lh * 4 + r;
                int col = nf * 16 + ll;
                sf[rowl * 68 + col] = acc[mf][nf][r] + bias[n0 + col];
            }
    __syncthreads();
#pragma unroll
    for (int p = 0; p < 8; p++) {
        int rowl = p * 16 + (tid >> 4);
        int col = (tid & 15) * 4;
        float4 v = *reinterpret_cast<const float4*>(&sf[rowl * 68 + col]);
        *reinterpret_cast<float4*>(outf + (size_t)(m0b + rowl) * N + n0 + col) = v;
    }
}

// ---------------- fused gate + ip GEMM (grid y: 0..3 gate cols, 4 = ip) ----------------
__global__ __launch_bounds__(256) void gateip_k(const unsigned short* __restrict__ xnb,
                                                const unsigned short* __restrict__ wg,
                                                const unsigned short* __restrict__ wip,
                                                const float* __restrict__ gbias, const float* __restrict__ ipb,
                                                const float* __restrict__ Bv, const float* __restrict__ bA,
                                                unsigned short* __restrict__ gB, float* __restrict__ u) {
    __shared__ char smem[128 * 72 * 2 > 128 * 68 * 4 ? 128 * 72 * 2 : 128 * 68 * 4];
    float* sf = (float*)smem;
    unsigned short* su = (unsigned short*)smem;
    const int tid = threadIdx.x, l = tid & 63, w = tid >> 6;
    const int ll = l & 15, lh = l >> 4;
    const int m0b = blockIdx.x * 128;
    const int m0 = m0b + w * 32;
    const int y = blockIdx.y;
    const bool gate = (y < 4);
    const int n0 = gate ? y * 64 : 0;
    f32x4 acc[2][4] = {};
    mfma_core<HD>(xnb, gate ? wg : wip, m0, n0, ll, lh, acc);
    if (gate) {
#pragma unroll
        for (int mf = 0; mf < 2; mf++)
#pragma unroll
            for (int nf = 0; nf < 4; nf++)
#pragma unroll
                for (int r = 0; r < 4; r++) {
                    int rowl = w * 32 + mf * 16 + lh * 4 + r;
                    int col = nf * 16 + ll;
                    float v = acc[mf][nf][r] + gbias[n0 + col];
                    su[rowl * 72 + col] = f2bf(1.f / (1.f + __expf(-v)));
                }
        __syncthreads();
#pragma unroll
        for (int p = 0; p < 8; p++) {
            int rowl = p * 16 + (tid >> 4);
            int col = (tid & 15) * 4;
            ushort4 v = *reinterpret_cast<const ushort4*>(&su[rowl * 72 + col]);
            *reinterpret_cast<ushort4*>(gB + (size_t)(m0b + rowl) * HD + n0 + col) = v;
        }
    } else {
#pragma unroll
        for (int mf = 0; mf < 2; mf++)
#pragma unroll
            for (int nf = 0; nf < 4; nf++)
#pragma unroll
                for (int r = 0; r < 4; r++) {
                    int rowl = w * 32 + mf * 16 + lh * 4 + r;
                    int col = nf * 16 + ll;
                    float v = acc[mf][nf][r] + ipb[col];
                    sf[rowl * 68 + col] = Bv[col] * v + bA[col];
                }
        __syncthreads();
#pragma unroll
        for (int p = 0; p < 8; p++) {
            int rowl = p * 16 + (tid >> 4);
            int col = (tid & 15) * 4;
            int m = m0b + rowl;           // bt-order
            int t = m & 2047, b2 = m >> 11;
            float4 v = *reinterpret_cast<const float4*>(&sf[rowl * 68 + col]);
            *reinterpret_cast<float4*>(u + ((size_t)((t << 3) + b2)) * 64 + col) = v;
        }
    }
}

// ---------------- fused Cm + proj + gated blend (BM=32, 2 waves, no redundancy) ----------------
template <bool WRITE_HB>
__global__ __launch_bounds__(128) void post2_k(const unsigned short* __restrict__ Hs,
                                               const unsigned short* __restrict__ wc,
                                               const float* __restrict__ bC,
                                               const unsigned short* __restrict__ wp,
                                               const float* __restrict__ pb,
                                               const unsigned short* __restrict__ gB,
                                               const unsigned short* __restrict__ xnb,
                                               float* __restrict__ h, unsigned short* __restrict__ hb) {
    __shared__ unsigned short ys[32 * 264];
    __shared__ float hnl[32 * 260];
    const int tid = threadIdx.x, l = tid & 63, w = tid >> 6;
    const int ll = l & 15, lh = l >> 4;
    const int m0 = blockIdx.x * 32;      // tb-order rows
    // phase 1: y = Hs @ Cm^T + bC  (K=64), wave w rows w*16..+15, all 256 cols
    {
        f32x4 acc[16] = {};
        const unsigned short* Ap = Hs + (size_t)(m0 + w * 16 + ll) * SD + lh * 8;
#pragma unroll
        for (int ks = 0; ks < 2; ks++) {
            int c0 = ks * 32;
            short8 a = *reinterpret_cast<const short8*>(Ap + c0);
#pragma unroll
            for (int nf = 0; nf < 16; nf++) {
                short8 b = *reinterpret_cast<const short8*>(wc + (size_t)(nf * 16 + ll) * SD + c0 + lh * 8);
                acc[nf] = __builtin_amdgcn_mfma_f32_16x16x32_bf16(a, b, acc[nf], 0, 0, 0);
            }
        }
#pragma unroll
        for (int nf = 0; nf < 16; nf++)
#pragma unroll
            for (int r = 0; r < 4; r++) {
                int rowl = w * 16 + lh * 4 + r;
                int col = nf * 16 + ll;
                ys[rowl * 264 + col] = f2bf(acc[nf][r] + bC[col]);
            }
    }
    __syncthreads();
    // phase 2: y2 = y @ proj^T (K=256)
    {
        f32x4 acc2[16] = {};
        const int arow = w * 16 + ll;
#pragma unroll
        for (int ks = 0; ks < 8; ks++) {
            int c0 = ks * 32 + lh * 8;
            short8 a = *reinterpret_cast<const short8*>(&ys[arow * 264 + c0]);
#pragma unroll
            for (int nf = 0; nf < 16; nf++) {
                short8 b = *reinterpret_cast<const short8*>(wp + (size_t)(nf * 16 + ll) * HD + c0);
                acc2[nf] = __builtin_amdgcn_mfma_f32_16x16x32_bf16(a, b, acc2[nf], 0, 0, 0);
            }
        }
#pragma unroll
        for (int nf = 0; nf < 16; nf++)
#pragma unroll
            for (int r = 0; r < 4; r++) {
                int rowl = w * 16 + lh * 4 + r;
                int col = nf * 16 + ll;
                hnl[rowl * 260 + col] = acc2[nf][r] + pb[col];
            }
    }
    __syncthreads();
    // phase 3: coalesced blend copy-out. 16 passes x (2 rows x 64 float4)
#pragma unroll
    for (int p = 0; p < 16; p++) {
        int rowl = p * 2 + (tid >> 6);
        int col = (tid & 63) * 4;
        int m = m0 + rowl;               // tb-order
        int t = m >> 3, b2 = m & 7;
        size_t gidx = ((size_t)((b2 << 11) + t)) * HD + col;
        float4 hv = *reinterpret_cast<const float4*>(h + gidx);
        ushort4 gv = *reinterpret_cast<const ushort4*>(gB + gidx);
        ushort4 xv = *reinterpret_cast<const ushort4*>(xnb + gidx);
        const float* vp = &hnl[rowl * 260 + col];
        float g0 = bf2f(gv.x), g1 = bf2f(gv.y), g2 = bf2f(gv.z), g3 = bf2f(gv.w);
        float o0 = hv.x + g0 * vp[0] + (1.f - g0) * bf2f(xv.x);
        float o1 = hv.y + g1 * vp[1] + (1.f - g1) * bf2f(xv.y);
        float o2 = hv.z + g2 * vp[2] + (1.f - g2) * bf2f(xv.z);
        float o3 = hv.w + g3 * vp[3] + (1.f - g3) * bf2f(xv.w);
        float4 ov; ov.x = o0; ov.y = o1; ov.z = o2; ov.w = o3;
        *reinterpret_cast<float4*>(h + gidx) = ov;
        if constexpr (WRITE_HB) {
            ushort4 hbv;
            hbv.x = f2bf(o0); hbv.y = f2bf(o1); hbv.z = f2bf(o2); hbv.w = f2bf(o3);
            *reinterpret_cast<ushort4*>(hb + gidx) = hbv;
        }
    }
}

// ---------------- scan helpers ----------------
__device__ __forceinline__ void loadA64(const float* __restrict__ Af, int s, float* a) {
#pragma unroll
    for (int q = 0; q < 16; q++) {
        float4 v = reinterpret_cast<const float4*>(Af + s * 64)[q];
        a[q * 4 + 0] = v.x; a[q * 4 + 1] = v.y; a[q * 4 + 2] = v.z; a[q * 4 + 3] = v.w;
    }
}

__device__ __forceinline__ float step64(const float* a, float h, float uu) {
    float ac0 = uu, ac1 = 0.f, ac2 = 0.f, ac3 = 0.f;
#pragma unroll
    for (int k = 0; k < 64; k += 4) {
        float b0 = __int_as_float(__builtin_amdgcn_readlane(__float_as_int(h), k + 0));
        float b1 = __int_as_float(__builtin_amdgcn_readlane(__float_as_int(h), k + 1));
        float b2 = __int_as_float(__builtin_amdgcn_readlane(__float_as_int(h), k + 2));
        float b3 = __int_as_float(__builtin_amdgcn_readlane(__float_as_int(h), k + 3));
        ac0 = fmaf(b0, a[k + 0], ac0);
        ac1 = fmaf(b1, a[k + 1], ac1);
        ac2 = fmaf(b2, a[k + 2], ac2);
        ac3 = fmaf(b3, a[k + 3], ac3);
    }
    return (ac0 + ac1) + (ac2 + ac3);
}

// pass 1: chunk-local linear scan; u preloaded to registers
__global__ __launch_bounds__(64) void scan_chunk_k(const float* __restrict__ Af,
                                                   const float* __restrict__ u,
                                                   float* __restrict__ Slast) {
    const int c = blockIdx.x >> 3, b = blockIdx.x & 7;
    const int s = threadIdx.x;
    float a[64];
    loadA64(Af, s, a);
    const float* up = u + (c * CLEN) * 512 + b * 64 + s;
    float uv[CLEN];
#pragma unroll
    for (int i = 0; i < CLEN; i++) uv[i] = up[i * 512];
    float h = 0.f;
#pragma unroll
    for (int i = 0; i < CLEN; i++) h = step64(a, h, uv[i]);
    Slast[blockIdx.x * 64 + s] = h;
}

// pass 2: carry across chunks; Slast preloaded
__global__ __launch_bounds__(64) void carry_k(const float* __restrict__ Apow,
                                              const float* __restrict__ Slast,
                                              float* __restrict__ Carry) {
    const int b = blockIdx.x;
    const int s = threadIdx.x;
    float a[64];
    loadA64(Apow, s, a);
    float sv[NCHUNK];
#pragma unroll
    for (int c = 0; c < NCHUNK; c++) sv[c] = Slast[(c * 8 + b) * 64 + s];
    float carry = 0.f;
#pragma unroll
    for (int c = 0; c < NCHUNK; c++) {
        Carry[(c * 8 + b) * 64 + s] = carry;
        carry = step64(a, carry, sv[c]);
    }
}

// pass 3: replay with true carry; u preloaded
__global__ __launch_bounds__(64) void replay_k(const float* __restrict__ Af,
                                               const float* __restrict__ u,
                                               const float* __restrict__ Carry,
                                               unsigned short* __restrict__ Hs,
                                               int* __restrict__ flag) {
    const int c = blockIdx.x >> 3, b = blockIdx.x & 7;
    const int s = threadIdx.x;
    float a[64];
    loadA64(Af, s, a);
    const float* up = u + (c * CLEN) * 512 + b * 64 + s;
    float uv[CLEN];
#pragma unroll
    for (int i = 0; i < CLEN; i++) uv[i] = up[i * 512];
    float h = Carry[blockIdx.x * 64 + s];
    unsigned short* hp = Hs + (c * CLEN) * 512 + b * 64 + s;
    bool bad = false;
#pragma unroll
    for (int i = 0; i < CLEN; i++) {
        h = step64(a, h, uv[i]);
        bad |= (fabsf(h) > 10.f);
        hp[i * 512] = f2bf(h);
    }
    if (__any(bad ? 1 : 0)) {
        if (s == 0) atomicOr(flag, 1);
    }
}

// pass 4: exact sequential fallback
__global__ __launch_bounds__(64) void scan_seq_k(const float* __restrict__ Af,
                                                 const float* __restrict__ u,
                                                 unsigned short* __restrict__ Hs,
                                                 const int* __restrict__ flag) {
    if (*flag == 0) return;
    const int b = blockIdx.x;
    const int s = threadIdx.x;
    float a[64];
    loadA64(Af, s, a);
    float h = 0.f;
    for (int t = 0; t < T_LEN; t++) {
        float uu = u[((t << 3) + b) * 64 + s];
        float hp = step64(a, h, uu);
        h = fminf(fmaxf(hp, -10.f), 10.f);
        Hs[((t << 3) + b) * 64 + s] = f2bf(h);
    }
}

// ---------------- launch ----------------
extern "C" void kernel_launch(void* const* d_in, const int* in_sizes, int n_in,
                              void* d_out, int out_size, void* d_ws, size_t ws_size,
                              hipStream_t stream) {
    const float* x    = (const float*)d_in[0];
    const float* inw  = (const float*)d_in[1];
    const float* inb  = (const float*)d_in[2];
    const float* lng  = (const float*)d_in[3];
    const float* lnb  = (const float*)d_in[4];
    const float* ipw  = (const float*)d_in[5];
    const float* ipb  = (const float*)d_in[6];
    const float* Amat = (const float*)d_in[7];
    const float* Bv   = (const float*)d_in[8];
    const float* Cm   = (const float*)d_in[9];
    const float* bA   = (const float*)d_in[10];
    const float* bC   = (const float*)d_in[11];
    const float* gw   = (const float*)d_in[12];
    const float* gbia = (const float*)d_in[13];
    const float* pw   = (const float*)d_in[14];
    const float* pb   = (const float*)d_in[15];
    const float* ow   = (const float*)d_in[16];
    const float* ob   = (const float*)d_in[17];

    char* ws = (char*)d_ws;
    unsigned short* xb = (unsigned short*)(ws + 0);          // 24 MB (reused below)
    float*          u  = (float*)(ws + 0);                   // 4 MB
    unsigned short* Hs = (unsigned short*)(ws + 4194304);    // 2 MB
    unsigned short* hb = (unsigned short*)(ws + 14680064);   // 8 MB
    unsigned short* wb = (unsigned short*)(ws + 25165824);   // 2 MB
    float*          h  = (float*)(ws + 27262976);            // 16 MB
    unsigned short* xnb = (unsigned short*)(ws + 44040192);  // 8 MB
    unsigned short* gB  = (unsigned short*)(ws + 52428800);  // 8 MB

    char* sc = (char*)d_out;   // small scratch; fully overwritten by final GEMM
    float* Apow  = (float*)(sc + 0);
    float* Slast = (float*)(sc + 65536);
    float* Carry = (float*)(sc + 131072);
    int*   flag  = (int*)(sc + 196608);

    const unsigned short* w_in = wb + 0;
    const unsigned short* w_ip = wb + 196608;
    const unsigned short* w_g  = wb + 262144;
    const unsigned short* w_p  = wb + 524288;
    const unsigned short* w_c  = wb + 786432;
    const unsigned short* w_o  = wb + 851968;

    hipMemsetAsync(flag, 0, 16, stream);
    cvt_x_k<<<12288, 256, 0, stream>>>(x, xb, 3145728);
    cvt_w_k<<<4096, 256, 0, stream>>>(inw, ipw, gw, pw, Cm, ow, wb);
    matpow_k<<<4, 256, 0, stream>>>(Amat, Apow);

    gemm_k<DIN, HD><<<dim3(128, 4), 256, 0, stream>>>(xb, w_in, inb, h);
    for (int i = 0; i < 4; i++) {
        ln_k<<<4096, 256, 0, stream>>>(h, lng + i * HD, lnb + i * HD, xnb);
        gateip_k<<<dim3(128, 5), 256, 0, stream>>>(xnb, w_g + i * 65536, w_ip + i * 16384,
                                                   gbia + i * HD, ipb + i * SD,
                                                   Bv + i * SD, bA + i * SD, gB, u);
        scan_chunk_k<<<256, 64, 0, stream>>>(Amat + i * 4096, u, Slast);
        carry_k<<<8, 64, 0, stream>>>(Apow + i * 4096, Slast, Carry);
        replay_k<<<256, 64, 0, stream>>>(Amat + i * 4096, u, Carry, Hs, flag + i);
        scan_seq_k<<<8, 64, 0, stream>>>(Amat + i * 4096, u, Hs, flag + i);
        if (i < 3)
            post2_k<false><<<512, 128, 0, stream>>>(Hs, w_c + i * 16384, bC + i * HD,
                                                    w_p + i * 65536, pb + i * HD, gB, xnb, h, hb);
        else
            post2_k<true><<<512, 128, 0, stream>>>(Hs, w_c + i * 16384, bC + i * HD,
                                                   w_p + i * 65536, pb + i * HD, gB, xnb, h, hb);
    }
    gemm_k<HD, DOUT><<<dim3(128, 12), 256, 0, stream>>>(hb, w_o, ob, (float*)d_out);
}